// Round 9
// baseline (246.771 us; speedup 1.0000x reference)
//
#include <hip/hip_runtime.h>
#include <cmath>

#define NA 3
#define HSIZE 8192
#define HMASK (HSIZE - 1)

typedef float v4f __attribute__((ext_vector_type(4)));

// ws layout:
//   0:      double sums[16]     [0]=nb_dense [1]=conf_dense [2]=c50_dense
//                               [3]=excl_nb [4]=excl_conf [5]=excl_cnt
//                               [6..9]=lx,ly,lw,lh [10]=bce_obj [11]=conf_obj
//                               [12]=i50det [13]=i75det [14]=n_obj
//   128:    int A_key[8192]  A_val[8192]  B_key[8192]  B_bits[8192]  B_maxt[8192]
//   then:   int ocell[T]  keyarr[T]

__device__ __forceinline__ float sigf(float v){ return 1.0f/(1.0f + expf(-v)); }
// fast path: v_exp_f32 + v_rcp_f32 (~1ulp) — dense bulk only
__device__ __forceinline__ float fast_sig(float v){
  return __builtin_amdgcn_rcpf(1.0f + __expf(-v));
}
__device__ __forceinline__ unsigned hslot(unsigned key){
  return (key * 2654435761u) >> 19;   // top 13 bits -> [0, 8192)
}

__global__ __launch_bounds__(256) void k_zero(int* __restrict__ p, int n){
  int i = blockIdx.x*256 + threadIdx.x;
  if (i < n) p[i] = 0;
}

__global__ __launch_bounds__(256) void k_targets(
    const float* __restrict__ targets, int T, int G, float stride,
    int* __restrict__ ocell, int* __restrict__ keyarr,
    int* __restrict__ A_key, int* __restrict__ A_val,
    int* __restrict__ B_key, int* __restrict__ B_bits, int* __restrict__ B_maxt)
{
  int t = blockIdx.x*256 + threadIdx.x;
  if (t >= T) return;
  const float* tr = targets + (size_t)t*6;
  int b = (int)tr[0];
  float gx = tr[2]*(float)G, gy = tr[3]*(float)G, gw = tr[4]*(float)G, gh = tr[5]*(float)G;
  float aw[NA] = {116.0f/stride, 156.0f/stride, 373.0f/stride};
  float ah[NA] = { 90.0f/stride, 198.0f/stride, 326.0f/stride};
  float best_iou = -1.0f; int best = 0; int bits = 0;
  #pragma unroll
  for (int a = 0; a < NA; ++a){
    float inter = fminf(aw[a], gw) * fminf(ah[a], gh);
    float uni   = aw[a]*ah[a] + gw*gh - inter;
    float iou   = inter / (uni + 1e-16f);
    if (iou > best_iou){ best_iou = iou; best = a; }
    if (iou > 0.5f) bits |= (1 << a);
  }
  bits |= (1 << best);
  int gi = (int)floorf(gx); gi = gi < 0 ? 0 : (gi > G-1 ? G-1 : gi);
  int gj = (int)floorf(gy); gj = gj < 0 ? 0 : (gj > G-1 ? G-1 : gj);
  int cell = (b*G + gj)*G + gi;             // < 2^21
  int okey = cell*4 + best;
  ocell[t]  = okey;
  keyarr[t] = (cell << 3) | bits;

  // table A: (cell,best) -> max t (last target wins scatter semantics)
  unsigned s = hslot((unsigned)okey) & HMASK;
  for (;;){
    int prev = atomicCAS(&A_key[s], 0, okey+1);
    if (prev == 0 || prev == okey+1){ atomicMax(&A_val[s], t+1); break; }
    s = (s+1) & HMASK;
  }
  // table B: cell -> union of excluded anchor bits, representative = max t
  s = hslot((unsigned)cell) & HMASK;
  for (;;){
    int prev = atomicCAS(&B_key[s], 0, cell+1);
    if (prev == 0 || prev == cell+1){
      atomicOr(&B_bits[s], bits);
      atomicMax(&B_maxt[s], t+1);
      break;
    }
    s = (s+1) & HMASK;
  }
}

// Fused kernel.
//   blocks [0, nblkT)   : sparse per-target path (scheduled FIRST)
//   blocks [nblkT, ...) : dense path — 8 cells/thread in TWO 4-cell chunks.
//     Thread tid owns block-local cells {tid*4..+3} and {1024+tid*4..+3}.
//     All 10 v4f loads issued up front (r8's MLP), then per chunk:
//     fast-math -> stage 20 floats (stride 21, conflict-free) into the
//     WAVE-LOCAL LDS region -> per-wave 1KB-contiguous NT stores.
//     The transpose is intra-wave (wave64 lockstep) -> NO block barrier;
//     chunk B reuses the same wave region.
// WHY: r8 proved {10-load MLP, line-coalesced stores, VGPR 68} = 75us at
// 3 WG/CU (42KB LDS). r1 proved occupancy alone (7 WG, 5-load) = 95us.
// This gets BOTH: LDS 21.9KB -> 7 WG/CU cap -> VGPR budget 512/7=73 >= ~68
// demand (no spill; the 32-reg clamp only appeared with tiny LDS).
// Per-thread 160B-strided direct stores are BANNED: partial-line NT flush
// inflated WRITE_SIZE 2.5-3.6x (r3/r4/r6/r7). Per-wave coalesced = 123MB.
// NO ticket finalize (r5: ~140us fence storm). k_final is its own launch.
__global__ __launch_bounds__(256) void k_main(
    const float* __restrict__ x, const float* __restrict__ targets,
    float* __restrict__ out, double* __restrict__ sums,
    int T, int G, float stride, int total_cells, int nblkT,
    const int* __restrict__ ocell, const int* __restrict__ keyarr,
    const int* __restrict__ A_key, const int* __restrict__ A_val,
    const int* __restrict__ B_key, const int* __restrict__ B_bits,
    const int* __restrict__ B_maxt)
{
  __shared__ float lds[4*64*21];   // 21,504 B — 4 wave-local transpose regions
  __shared__ double sred[4][12];
  int tid = threadIdx.x;
  int lane = tid & 63, wv = tid >> 6;

  if ((int)blockIdx.x < nblkT){
    // -------------------- sparse target path (precise math) --------------------
    int t = blockIdx.x*256 + tid;
    double v[12];
    #pragma unroll
    for (int k = 0; k < 12; ++k) v[k] = 0.0;
    // v: [0]=excl_nb [1]=excl_conf [2]=excl_cnt [3..6]=lx,ly,lw,lh
    //    [7]=bce [8]=conf_obj [9]=i50 [10]=i75 [11]=n_obj

    if (t < T){
      const float* tr = targets + (size_t)t*6;
      int b = (int)tr[0];
      float gx = tr[2]*(float)G, gy = tr[3]*(float)G, gw = tr[4]*(float)G, gh = tr[5]*(float)G;
      int okey = ocell[t];
      int myk  = keyarr[t];
      int cell = myk >> 3;
      int best = okey & 3;
      int gi = cell % G;
      int gj = (cell / G) % G;
      int GG = G*G;

      // ownership lookup (last target wins)
      unsigned s = hslot((unsigned)okey) & HMASK;
      while (A_key[s] != okey+1) s = (s+1) & HMASK;
      bool owner = (A_val[s] == t+1);

      if (owner){
        float awb = (best==0 ? 116.0f : (best==1 ? 156.0f : 373.0f)) / stride;
        float ahb = (best==0 ?  90.0f : (best==1 ? 198.0f : 326.0f)) / stride;
        const float* xp = x + ((size_t)(b*(NA*5) + best*5))*GG + (size_t)gj*G + gi;
        float x0 = xp[0], x1 = xp[(size_t)GG], x2 = xp[(size_t)2*GG],
              x3 = xp[(size_t)3*GG], x4 = xp[(size_t)4*GG];
        float cx = sigf(x0), cy = sigf(x1), w = x2, h = x3, conf = sigf(x4);
        float tx = gx - (float)gi, ty = gy - (float)gj;
        float tw = logf(gw/awb + 1e-16f), th = logf(gh/ahb + 1e-16f);
        v[3] = (double)((cx-tx)*(cx-tx));
        v[4] = (double)((cy-ty)*(cy-ty));
        v[5] = (double)((w-tw)*(w-tw));
        v[6] = (double)((h-th)*(h-th));
        v[7] = (double)(-logf(conf + 1e-12f));
        v[8] = (double)conf;
        float px = (float)gi + cx, py = (float)gj + cy;
        float pw = expf(w)*awb, ph = expf(h)*ahb;
        float iw = fminf(px + pw*0.5f, gx + gw*0.5f) - fmaxf(px - pw*0.5f, gx - gw*0.5f);
        float ih = fminf(py + ph*0.5f, gy + gh*0.5f) - fmaxf(py - ph*0.5f, gy - gh*0.5f);
        iw = fmaxf(iw, 0.0f); ih = fmaxf(ih, 0.0f);
        float inter = iw*ih;
        float iou = inter / (pw*ph + gw*gh - inter + 1e-16f);
        bool det = conf > 0.5f;
        v[9]  = (iou > 0.5f  && det) ? 1.0 : 0.0;
        v[10] = (iou > 0.75f && det) ? 1.0 : 0.0;
        v[11] = 1.0;
      }

      // exclusion: representative per distinct cell processes the bit union
      s = hslot((unsigned)cell) & HMASK;
      while (B_key[s] != cell+1) s = (s+1) & HMASK;
      if (B_maxt[s] == t+1){
        int bits = B_bits[s];
        #pragma unroll
        for (int a = 0; a < NA; ++a){
          if (bits & (1 << a)){
            float x4 = x[((size_t)(b*(NA*5) + a*5 + 4))*GG + (size_t)gj*G + gi];
            float conf = sigf(x4);
            v[0] += (double)(-logf(1.0f - conf + 1e-12f));
            v[1] += (double)conf;
            v[2] += 1.0;
          }
        }
      }
    }

    #pragma unroll
    for (int k = 0; k < 12; ++k){
      #pragma unroll
      for (int off = 32; off > 0; off >>= 1) v[k] += __shfl_down(v[k], off);
    }
    if (lane == 0){
      #pragma unroll
      for (int k = 0; k < 12; ++k) sred[wv][k] = v[k];
    }
    __syncthreads();
    if (tid < 12){
      double sm = sred[0][tid] + sred[1][tid] + sred[2][tid] + sred[3][tid];
      unsafeAtomicAdd(&sums[3 + tid], sm);
    }
  } else {
    // -------- dense path: 2 chunks x 4 cells, wave-local transpose --------
    int dblk = blockIdx.x - nblkT;
    int GG = G*G;
    int blockCell = dblk*2048;
    int cellA = blockCell + tid*4;
    int cellB = cellA + 1024;
    float nb = 0.0f, cs = 0.0f; int c50 = 0;

    bool okA = (cellA < total_cells), okB = (cellB < total_cells);

    // ---- issue ALL 10 loads up front (per-thread MLP = r8's) ----
    v4f a0,a1,a2,a3,a4, b0,b1,b2,b3,b4;
    int gxA=0,gyA=0,plA=0, gxB=0,gyB=0,plB=0;
    if (okA){
      gxA = cellA % G; int rowA = cellA / G; gyA = rowA % G; plA = rowA / G;
      const float* xbA = x + (size_t)plA*5*GG + (size_t)gyA*G + gxA;
      a0 = *(const v4f*)(xbA);
      a1 = *(const v4f*)(xbA + (size_t)GG);
      a2 = *(const v4f*)(xbA + (size_t)2*GG);
      a3 = *(const v4f*)(xbA + (size_t)3*GG);
      a4 = *(const v4f*)(xbA + (size_t)4*GG);
    }
    if (okB){
      gxB = cellB % G; int rowB = cellB / G; gyB = rowB % G; plB = rowB / G;
      const float* xbB = x + (size_t)plB*5*GG + (size_t)gyB*G + gxB;
      b0 = *(const v4f*)(xbB);
      b1 = *(const v4f*)(xbB + (size_t)GG);
      b2 = *(const v4f*)(xbB + (size_t)2*GG);
      b3 = *(const v4f*)(xbB + (size_t)3*GG);
      b4 = *(const v4f*)(xbB + (size_t)4*GG);
    }

    float* myl = lds + (size_t)wv*1344 + (size_t)lane*21;   // wave-local slot
    const float* wl = lds + (size_t)wv*1344;
    size_t totalF = (size_t)total_cells*5;

    // ---------------- chunk A: compute + stage + wave store ----------------
    if (okA){
      int aA = plA % NA;
      float aw = (aA==0 ? 116.0f : (aA==1 ? 156.0f : 373.0f)) / stride;
      float ah = (aA==0 ?  90.0f : (aA==1 ? 198.0f : 326.0f)) / stride;
      #pragma unroll
      for (int j = 0; j < 4; ++j){
        float cx   = fast_sig(a0[j]);
        float cy   = fast_sig(a1[j]);
        float pw   = __expf(a2[j])*aw;
        float ph   = __expf(a3[j])*ah;
        float conf = fast_sig(a4[j]);
        myl[j*5+0] = ((float)(gxA + j) + cx)*stride;
        myl[j*5+1] = ((float)gyA + cy)*stride;
        myl[j*5+2] = pw*stride;
        myl[j*5+3] = ph*stride;
        myl[j*5+4] = conf;
        nb -= __logf(1.0f - conf + 1e-12f);
        cs += conf;
        c50 += (conf > 0.5f) ? 1 : 0;
      }
    }
    __builtin_amdgcn_wave_barrier();
    {
      // wave wv covers chunk-A cells [blockCell + wv*256, +256) = 1280 floats
      size_t outBase = (size_t)dblk*10240 + (size_t)wv*1280;
      if (outBase < totalF){
        #pragma unroll
        for (int c = 0; c < 5; ++c){
          int f = (c*64 + lane)*4;        // [0, 1280)
          int owner = f / 20;
          int within = f - owner*20;
          const float* src = wl + owner*21 + within;
          v4f val;
          val.x = src[0]; val.y = src[1]; val.z = src[2]; val.w = src[3];
          __builtin_nontemporal_store(val, (v4f*)(out + outBase + f));
        }
      }
    }
    __builtin_amdgcn_wave_barrier();

    // ---------------- chunk B: compute + stage + wave store ----------------
    if (okB){
      int aB = plB % NA;
      float aw = (aB==0 ? 116.0f : (aB==1 ? 156.0f : 373.0f)) / stride;
      float ah = (aB==0 ?  90.0f : (aB==1 ? 198.0f : 326.0f)) / stride;
      #pragma unroll
      for (int j = 0; j < 4; ++j){
        float cx   = fast_sig(b0[j]);
        float cy   = fast_sig(b1[j]);
        float pw   = __expf(b2[j])*aw;
        float ph   = __expf(b3[j])*ah;
        float conf = fast_sig(b4[j]);
        myl[j*5+0] = ((float)(gxB + j) + cx)*stride;
        myl[j*5+1] = ((float)gyB + cy)*stride;
        myl[j*5+2] = pw*stride;
        myl[j*5+3] = ph*stride;
        myl[j*5+4] = conf;
        nb -= __logf(1.0f - conf + 1e-12f);
        cs += conf;
        c50 += (conf > 0.5f) ? 1 : 0;
      }
    }
    __builtin_amdgcn_wave_barrier();
    {
      size_t outBase = (size_t)dblk*10240 + 5120 + (size_t)wv*1280;
      if (outBase < totalF){
        #pragma unroll
        for (int c = 0; c < 5; ++c){
          int f = (c*64 + lane)*4;        // [0, 1280)
          int owner = f / 20;
          int within = f - owner*20;
          const float* src = wl + owner*21 + within;
          v4f val;
          val.x = src[0]; val.y = src[1]; val.z = src[2]; val.w = src[3];
          __builtin_nontemporal_store(val, (v4f*)(out + outBase + f));
        }
      }
    }

    // ---------------- block reduction (only block-wide sync point) ----------
    float vals[3] = {nb, cs, (float)c50};
    #pragma unroll
    for (int k = 0; k < 3; ++k){
      #pragma unroll
      for (int off = 32; off > 0; off >>= 1) vals[k] += __shfl_down(vals[k], off);
    }
    if (lane == 0){
      sred[wv][0] = (double)vals[0];
      sred[wv][1] = (double)vals[1];
      sred[wv][2] = (double)vals[2];
    }
    __syncthreads();
    if (tid < 3){
      double sm = sred[0][tid] + sred[1][tid] + sred[2][tid] + sred[3][tid];
      unsafeAtomicAdd(&sums[tid], sm);
    }
  }
}

__global__ __launch_bounds__(64) void k_final(
    const double* __restrict__ sums, float* __restrict__ tail, double total_cells)
{
  if (threadIdx.x != 0) return;
  double nb_all = sums[0], conf_all = sums[1], c50_all = sums[2];
  double enb = sums[3], econf = sums[4], ecnt = sums[5];
  double lx = sums[6], ly = sums[7], lw = sums[8], lh = sums[9];
  double bce = sums[10], cobj = sums[11], i50 = sums[12], i75 = sums[13], nobj = sums[14];

  double dObj = fmax(nobj, 1.0);
  double n_noobj = total_cells - ecnt;
  double dNo  = fmax(n_noobj, 1.0);

  double loss_x = lx/dObj, loss_y = ly/dObj, loss_w = lw/dObj, loss_h = lh/dObj;
  double loss_bbox = loss_x + loss_y + loss_w + loss_h;
  double loss_conf_obj   = bce/dObj;
  double loss_conf_noobj = (nb_all - enb)/dNo;
  double loss_conf  = 100.0*loss_conf_obj + 1.0*loss_conf_noobj;
  double loss_layer = loss_bbox + loss_conf;
  double conf_obj   = cobj/dObj;
  double conf_noobj = (conf_all - econf)/dNo;
  double precision  = i50/(c50_all + 1e-16);
  double recall50   = i50/(nobj + 1e-16);
  double recall75   = i75/(nobj + 1e-16);

  tail[0]  = (float)loss_layer;
  tail[1]  = (float)loss_x;
  tail[2]  = (float)loss_y;
  tail[3]  = (float)loss_w;
  tail[4]  = (float)loss_h;
  tail[5]  = (float)loss_bbox;
  tail[6]  = (float)loss_conf;
  tail[7]  = (float)loss_layer;
  tail[8]  = (float)conf_obj;
  tail[9]  = (float)conf_noobj;
  tail[10] = (float)precision;
  tail[11] = (float)recall50;
  tail[12] = (float)recall75;
}

extern "C" void kernel_launch(void* const* d_in, const int* in_sizes, int n_in,
                              void* d_out, int out_size, void* d_ws, size_t ws_size,
                              hipStream_t stream) {
  const float* x       = (const float*)d_in[0];
  const float* targets = (const float*)d_in[1];
  float* out = (float*)d_out;

  const int B = 32;
  int GG = in_sizes[0] / (B * NA * 5);
  int G = (int)(sqrt((double)GG) + 0.5);
  int T = in_sizes[1] / 6;
  float stride = 2048.0f / (float)G;

  char* ws = (char*)d_ws;
  double* sums  = (double*)ws;
  int* A_key  = (int*)(ws + 128);
  int* A_val  = A_key + HSIZE;
  int* B_key  = A_val + HSIZE;
  int* B_bits = B_key + HSIZE;
  int* B_maxt = B_bits + HSIZE;
  int* ocell  = B_maxt + HSIZE;
  int* keyarr = ocell + T;

  int total_cells = B * NA * GG;            // 6,291,456
  int nzero = 32 + 5*HSIZE;                 // sums (as ints) + tables
  int nblkZ = (nzero + 255) / 256;
  int nblkT = (T + 255) / 256;
  int nblkD = (total_cells + 2047) / 2048;  // 3072 (8 cells/thread, 2 chunks)

  k_zero   <<<nblkZ, 256, 0, stream>>>((int*)ws, nzero);
  k_targets<<<nblkT, 256, 0, stream>>>(targets, T, G, stride, ocell, keyarr,
                                       A_key, A_val, B_key, B_bits, B_maxt);
  k_main   <<<nblkT + nblkD, 256, 0, stream>>>(x, targets, out, sums,
                                       T, G, stride, total_cells, nblkT,
                                       ocell, keyarr,
                                       A_key, A_val, B_key, B_bits, B_maxt);
  k_final  <<<1, 64, 0, stream>>>(sums, out + (size_t)total_cells*5, (double)total_cells);
}